// Round 7
// baseline (364.524 us; speedup 1.0000x reference)
//
#include <hip/hip_runtime.h>
#include <math.h>

// GCN 2-layer, N=100000, E=6400000, Fin=1, Fhid=16, Fout=2.
// R7: FULL dst-sort, zero-atomic aggregation.
//   Stage A (R6-proven): coarse counting sort into 98 buckets of 1024 nodes
//     (k_hist -> k_scan -> k_place), packed = (dst&1023)<<17 | src.
//   Stage B: fine sort to full dst order: k_deg builds per-(bucket,split)
//     node histograms (the only remaining LDS-atomic passes are the sort
//     itself); k_fscan scans them into node run offsets NodeOff + per-split
//     write cursors W, and computes dinv/y; k_fplace scatters src indices
//     into packed2 (writes land in 256KB L2-resident bucket windows).
//   Stage C: aggregation = register-accumulated run walks, thread-per-node,
//     NO atomics, NO LDS: k_agg1m fuses layer1-sum + 1->16 relu MLP -> 16->2
//     (writes gy premultiplied by dinv); k_agg2o fuses layer2-sum + bias +
//     log_softmax -> out.
// R6 post-mortem: agg kernels were LDS-atomic-throughput bound (2.5-3 cyc per
// random ds_add, one LDS unit/CU); occupancy/unroll were neutral. This build
// moves all randomness into the sort and makes aggregation load-only.

#define CSH   10
#define CMASK 1023
#define C     1024
#define B1    256      // coarse sort blocks; chunk = E/B1 = 25000 (/4 exact)
#define S     8        // splits per bucket in fine stage
#define SCAN_T 512
#define AT    512      // threads for k_deg / k_fplace

// --- coarse histogram of dst>>10 (4 per-wave sub-hists, 128 slots each)
__global__ __launch_bounds__(256) void k_hist(const int* __restrict__ dst,
                                              int* __restrict__ G,
                                              int chunk, int nbkt) {
    __shared__ int sh[512];
    int t = threadIdx.x, blk = blockIdx.x;
    sh[t] = 0; sh[t + 256] = 0;
    __syncthreads();
    int w = (t >> 6) << 7;
    const int4* d4 = (const int4*)(dst + blk * chunk);
    int n4 = chunk >> 2;
    for (int i = t; i < n4; i += 256) {
        int4 d = d4[i];
        atomicAdd(&sh[w + (d.x >> CSH)], 1);
        atomicAdd(&sh[w + (d.y >> CSH)], 1);
        atomicAdd(&sh[w + (d.z >> CSH)], 1);
        atomicAdd(&sh[w + (d.w >> CSH)], 1);
    }
    __syncthreads();
    if (t < nbkt)
        G[t * B1 + blk] = sh[t] + sh[128 + t] + sh[256 + t] + sh[384 + t];
}

// --- single-block exclusive scan over G[NP] (bucket-major)
__global__ __launch_bounds__(SCAN_T) void k_scan(int* __restrict__ G, int NP) {
    __shared__ int sh[SCAN_T];
    int t = threadIdx.x;
    int carry = 0;
    for (int base = 0; base < NP; base += SCAN_T) {
        int i = base + t;
        int v = (i < NP) ? G[i] : 0;
        sh[t] = v;
        __syncthreads();
        for (int off = 1; off < SCAN_T; off <<= 1) {
            int u = (t >= off) ? sh[t - off] : 0;
            __syncthreads();
            sh[t] += u;
            __syncthreads();
        }
        if (i < NP) G[i] = carry + sh[t] - v;
        carry += sh[SCAN_T - 1];
        __syncthreads();
    }
}

// --- coarse scatter into bucket order
__global__ __launch_bounds__(256) void k_place(const int* __restrict__ src,
                                               const int* __restrict__ dst,
                                               const int* __restrict__ Gs,
                                               int* __restrict__ packed,
                                               int chunk, int nbkt) {
    __shared__ int offs[128];
    int t = threadIdx.x, blk = blockIdx.x;
    if (t < nbkt) offs[t] = Gs[t * B1 + blk];
    __syncthreads();
    int s0 = blk * chunk, n4 = chunk >> 2;
    const int4* d4 = (const int4*)(dst + s0);
    const int4* s4 = (const int4*)(src + s0);
    for (int i = t; i < n4; i += 256) {
        int4 d = d4[i];
        int4 s = s4[i];
        int b, p;
        b = d.x >> CSH; p = atomicAdd(&offs[b], 1); packed[p] = ((d.x & CMASK) << 17) | s.x;
        b = d.y >> CSH; p = atomicAdd(&offs[b], 1); packed[p] = ((d.y & CMASK) << 17) | s.y;
        b = d.z >> CSH; p = atomicAdd(&offs[b], 1); packed[p] = ((d.z & CMASK) << 17) | s.z;
        b = d.w >> CSH; p = atomicAdd(&offs[b], 1); packed[p] = ((d.w & CMASK) << 17) | s.w;
    }
}

// --- fine histogram: block (b,s) counts node-locals of its 1/S of bucket b
__global__ __launch_bounds__(AT) void k_deg(const int* __restrict__ packed,
                                            const int* __restrict__ Gs,
                                            int* __restrict__ Pdeg,
                                            int E, int nbkt) {
    __shared__ int cnt[C];
    int t = threadIdx.x, g = blockIdx.x;
    int b = g >> 3, s = g & 7;
    cnt[t] = 0; cnt[t + AT] = 0;
    __syncthreads();
    int st = Gs[b * B1];
    int en = (b == nbkt - 1) ? E : Gs[(b + 1) * B1];
    int len = en - st;
    int lo = st + ((len * s) >> 3);
    int hi = st + ((len * (s + 1)) >> 3);
    int i = lo + t;
    for (; i + 3 * AT < hi; i += 4 * AT) {
        int p0 = packed[i], p1 = packed[i + AT], p2 = packed[i + 2 * AT], p3 = packed[i + 3 * AT];
        atomicAdd(&cnt[p0 >> 17], 1);
        atomicAdd(&cnt[p1 >> 17], 1);
        atomicAdd(&cnt[p2 >> 17], 1);
        atomicAdd(&cnt[p3 >> 17], 1);
    }
    for (; i < hi; i += AT)
        atomicAdd(&cnt[packed[i] >> 17], 1);
    __syncthreads();
    Pdeg[(size_t)g * C + t] = cnt[t];
    Pdeg[(size_t)g * C + t + AT] = cnt[t + AT];
}

// --- per-bucket scan of node totals -> NodeOff, per-split cursors W, dinv, y
__global__ __launch_bounds__(1024) void k_fscan(const int* __restrict__ Pdeg,
                                                const int* __restrict__ Gs,
                                                const float* __restrict__ x,
                                                int* __restrict__ W,
                                                int* __restrict__ NodeOff,
                                                float* __restrict__ dinv,
                                                float* __restrict__ y,
                                                int N, int E, int nbkt) {
    __shared__ int sh[C];
    int b = blockIdx.x, l = threadIdx.x;
    int c[S];
    int tot = 0;
#pragma unroll
    for (int s = 0; s < S; s++) {
        c[s] = Pdeg[(size_t)(b * S + s) * C + l];
        tot += c[s];
    }
    sh[l] = tot;
    __syncthreads();
    for (int off = 1; off < C; off <<= 1) {
        int u = (l >= off) ? sh[l - off] : 0;
        __syncthreads();
        sh[l] += u;
        __syncthreads();
    }
    int start = Gs[b * B1] + sh[l] - tot;   // bucket base + exclusive prefix
    int node = (b << CSH) + l;
    NodeOff[node] = start;
    if (b == nbkt - 1 && l == C - 1) NodeOff[node + 1] = E;
    int run = start;
#pragma unroll
    for (int s = 0; s < S; s++) {
        W[(size_t)(b * S + s) * C + l] = run;
        run += c[s];
    }
    if (node < N) {
        float di = rsqrtf((float)tot + 1.0f);   // +1 self-loop
        dinv[node] = di;
        y[node] = di * x[node];
    }
}

// --- fine scatter: full dst order, store src index only
__global__ __launch_bounds__(AT) void k_fplace(const int* __restrict__ packed,
                                               const int* __restrict__ Gs,
                                               const int* __restrict__ W,
                                               int* __restrict__ packed2,
                                               int E, int nbkt) {
    __shared__ int cur[C];
    int t = threadIdx.x, g = blockIdx.x;
    int b = g >> 3, s = g & 7;
    cur[t] = W[(size_t)g * C + t];
    cur[t + AT] = W[(size_t)g * C + t + AT];
    __syncthreads();
    int st = Gs[b * B1];
    int en = (b == nbkt - 1) ? E : Gs[(b + 1) * B1];
    int len = en - st;
    int lo = st + ((len * s) >> 3);
    int hi = st + ((len * (s + 1)) >> 3);
    int i = lo + t;
    for (; i + 3 * AT < hi; i += 4 * AT) {
        int p0 = packed[i], p1 = packed[i + AT], p2 = packed[i + 2 * AT], p3 = packed[i + 3 * AT];
        int q0 = atomicAdd(&cur[p0 >> 17], 1);
        int q1 = atomicAdd(&cur[p1 >> 17], 1);
        int q2 = atomicAdd(&cur[p2 >> 17], 1);
        int q3 = atomicAdd(&cur[p3 >> 17], 1);
        packed2[q0] = p0 & 0x1FFFF;
        packed2[q1] = p1 & 0x1FFFF;
        packed2[q2] = p2 & 0x1FFFF;
        packed2[q3] = p3 & 0x1FFFF;
    }
    for (; i < hi; i += AT) {
        int p = packed[i];
        int q = atomicAdd(&cur[p >> 17], 1);
        packed2[q] = p & 0x1FFFF;
    }
}

// --- layer-1: register run-sum + fused 1->16 relu MLP -> 16->2 (no atomics)
__global__ __launch_bounds__(128) void k_agg1m(const int* __restrict__ packed2,
                                               const int* __restrict__ NodeOff,
                                               const float* __restrict__ dinv,
                                               const float* __restrict__ y,
                                               const float* __restrict__ W1,
                                               const float* __restrict__ b1,
                                               const float* __restrict__ W2,
                                               float2* __restrict__ gy, int N) {
    int node = blockIdx.x * 128 + threadIdx.x;
    int st = NodeOff[node], en = NodeOff[node + 1];
    float sum = 0.f;
    int i = st;
    for (; i + 3 < en; i += 4) {
        int s0 = packed2[i], s1 = packed2[i + 1], s2 = packed2[i + 2], s3 = packed2[i + 3];
        sum += y[s0] + y[s1] + y[s2] + y[s3];
    }
    for (; i < en; i++) sum += y[packed2[i]];
    if (node < N) {
        float di = dinv[node];
        float Sv = di * (sum + y[node]);        // self-loop adds y[node]
        float g0 = 0.f, g1 = 0.f;
#pragma unroll
        for (int f = 0; f < 16; f++) {
            float h = fmaxf(fmaf(W1[f], Sv, b1[f]), 0.f);
            g0 = fmaf(h, W2[2 * f], g0);
            g1 = fmaf(h, W2[2 * f + 1], g1);
        }
        gy[node] = make_float2(di * g0, di * g1);  // premultiplied by dinv[src]
    }
}

// --- layer-2: register run-sum + bias + log_softmax (no atomics)
__global__ __launch_bounds__(128) void k_agg2o(const int* __restrict__ packed2,
                                               const int* __restrict__ NodeOff,
                                               const float* __restrict__ dinv,
                                               const float2* __restrict__ gy,
                                               const float* __restrict__ b2,
                                               float2* __restrict__ out, int N) {
    int node = blockIdx.x * 128 + threadIdx.x;
    int st = NodeOff[node], en = NodeOff[node + 1];
    float t0 = 0.f, t1 = 0.f;
    int i = st;
    for (; i + 3 < en; i += 4) {
        float2 v0 = gy[packed2[i]];
        float2 v1 = gy[packed2[i + 1]];
        float2 v2 = gy[packed2[i + 2]];
        float2 v3 = gy[packed2[i + 3]];
        t0 += v0.x + v1.x + v2.x + v3.x;
        t1 += v0.y + v1.y + v2.y + v3.y;
    }
    for (; i < en; i++) {
        float2 v = gy[packed2[i]];
        t0 += v.x; t1 += v.y;
    }
    if (node < N) {
        float di = dinv[node];
        float2 g = gy[node];
        float z0 = di * (t0 + g.x) + b2[0];
        float z1 = di * (t1 + g.y) + b2[1];
        float m = fmaxf(z0, z1);
        float lse = logf(expf(z0 - m) + expf(z1 - m));
        out[node] = make_float2(z0 - m - lse, z1 - m - lse);
    }
}

extern "C" void kernel_launch(void* const* d_in, const int* in_sizes, int n_in,
                              void* d_out, int out_size, void* d_ws, size_t ws_size,
                              hipStream_t stream) {
    const float* x  = (const float*)d_in[0];
    const int* ei   = (const int*)d_in[1];
    const float* W1 = (const float*)d_in[2];
    const float* b1 = (const float*)d_in[3];
    const float* W2 = (const float*)d_in[4];
    const float* b2 = (const float*)d_in[5];

    const int N = in_sizes[0];        // 100000
    const int E = in_sizes[1] / 2;    // 6400000
    const int* src = ei;
    const int* dst = ei + E;

    const int nbkt  = (N + CMASK) >> CSH;    // 98
    const int chunk = E / B1;                // 25000
    const int NP    = nbkt * B1;             // 25088
    const int gF    = nbkt * S;              // 784 fine blocks
    const int np    = nbkt << CSH;           // 100352 (padded nodes)

    // ws layout (ints):
    // packed[E] | G[NP] | Pdeg[gF*C] | W[gF*C] | NodeOff[np+1] |
    // dinv[np] | y[np] | gy[2np] | [packed2[E] if it fits, else in d_in[1]]
    int* packed  = (int*)d_ws;
    int* G       = packed + E;
    int* Pdeg    = G + NP;
    int* W       = Pdeg + (size_t)gF * C;
    int* NodeOff = W + (size_t)gF * C;
    float* dinv  = (float*)(NodeOff + np + 1);
    float* y     = dinv + np;
    float2* gy   = (float2*)(y + np);
    int* tail    = (int*)(gy + np);
    size_t used  = (size_t)((char*)tail - (char*)d_ws);
    // packed2 in workspace if it fits; else reuse the (already-consumed-by-
    // then) edge_index src region — harness restores d_in before every launch,
    // and every slot of packed2 is rewritten each launch before being read.
    int* packed2 = (used + (size_t)E * sizeof(int) <= ws_size)
                       ? tail : (int*)d_in[1];

    k_hist  <<<B1,        256,    0, stream>>>(dst, G, chunk, nbkt);
    k_scan  <<<1,         SCAN_T, 0, stream>>>(G, NP);
    k_place <<<B1,        256,    0, stream>>>(src, dst, G, packed, chunk, nbkt);
    k_deg   <<<gF,        AT,     0, stream>>>(packed, G, Pdeg, E, nbkt);
    k_fscan <<<nbkt,      C,      0, stream>>>(Pdeg, G, x, W, NodeOff, dinv, y, N, E, nbkt);
    k_fplace<<<gF,        AT,     0, stream>>>(packed, G, W, packed2, E, nbkt);
    k_agg1m <<<np / 128,  128,    0, stream>>>(packed2, NodeOff, dinv, y, W1, b1, W2, gy, N);
    k_agg2o <<<np / 128,  128,    0, stream>>>(packed2, NodeOff, dinv, gy, b2, (float2*)d_out, N);
}

// Round 8
// 319.754 us; speedup vs baseline: 1.1400x; 1.1400x over previous
//
#include <hip/hip_runtime.h>
#include <math.h>

// GCN 2-layer, N=100000, E=6400000, Fin=1, Fhid=16, Fout=2.
// R8 = R7 (two-level counting sort to full dst order; zero-atomic register
// run-walk aggregation) with two fixes from R7's profile:
//  1. k_scan was a single-block serial scan: 66us @ 0.086% occupancy.
//     -> 3-phase parallel scan (R4-proven): ~5us. NP=25088=49*512 exactly.
//  2. k_fplace wrote ~32B chunks scattered over 256KB windows (partial-line
//     churn). -> node-partitioned: each fine block OWNS 128 nodes, reads the
//     whole bucket's packed range (L2/L3-resident), filters its ~1/8 of
//     edges into a 48KB LDS staging buffer via cursor bumps, flushes fully
//     coalesced. W table deleted (cursors derive from NodeOff). Guaranteed
//     fallback to direct scatter if staging overflows (12288 cap vs 8163
//     expected, ~46 sigma).
// packed  = (dst & 1023) << 17 | src   (src < 2^17); packed2 = src only.

#define CSH   10
#define CMASK 1023
#define C     1024
#define B1    256      // coarse sort blocks; chunk = E/B1 = 25000 (/4 exact)
#define S     8        // fine splits per bucket (128 nodes each)
#define SCAN_T 512
#define AT    512      // threads for k_deg
#define FCAP  12288    // staging ints in k_fplace (48 KB)

// --- coarse histogram of dst>>10 (4 per-wave sub-hists, 128 slots each)
__global__ __launch_bounds__(256) void k_hist(const int* __restrict__ dst,
                                              int* __restrict__ G,
                                              int chunk, int nbkt) {
    __shared__ int sh[512];
    int t = threadIdx.x, blk = blockIdx.x;
    sh[t] = 0; sh[t + 256] = 0;
    __syncthreads();
    int w = (t >> 6) << 7;
    const int4* d4 = (const int4*)(dst + blk * chunk);
    int n4 = chunk >> 2;
    for (int i = t; i < n4; i += 256) {
        int4 d = d4[i];
        atomicAdd(&sh[w + (d.x >> CSH)], 1);
        atomicAdd(&sh[w + (d.y >> CSH)], 1);
        atomicAdd(&sh[w + (d.z >> CSH)], 1);
        atomicAdd(&sh[w + (d.w >> CSH)], 1);
    }
    __syncthreads();
    if (t < nbkt)
        G[t * B1 + blk] = sh[t] + sh[128 + t] + sh[256 + t] + sh[384 + t];
}

// --- 3-phase parallel exclusive scan over G[NP] (bucket-major), R4-proven
__global__ __launch_bounds__(SCAN_T) void k_scan1(int* __restrict__ G,
                                                  int* __restrict__ part, int NG) {
    __shared__ int sh[SCAN_T];
    int t = threadIdx.x;
    int i = blockIdx.x * SCAN_T + t;
    int v = (i < NG) ? G[i] : 0;
    sh[t] = v;
    __syncthreads();
    for (int off = 1; off < SCAN_T; off <<= 1) {
        int u = (t >= off) ? sh[t - off] : 0;
        __syncthreads();
        sh[t] += u;
        __syncthreads();
    }
    if (i < NG) G[i] = sh[t] - v;
    if (t == SCAN_T - 1) part[blockIdx.x] = sh[t];
}

__global__ __launch_bounds__(SCAN_T) void k_scan2(int* __restrict__ part, int NP) {
    __shared__ int sh[SCAN_T];
    int t = threadIdx.x;
    int carry = 0;
    for (int base = 0; base < NP; base += SCAN_T) {
        int i = base + t;
        int v = (i < NP) ? part[i] : 0;
        sh[t] = v;
        __syncthreads();
        for (int off = 1; off < SCAN_T; off <<= 1) {
            int u = (t >= off) ? sh[t - off] : 0;
            __syncthreads();
            sh[t] += u;
            __syncthreads();
        }
        if (i < NP) part[i] = carry + sh[t] - v;
        carry += sh[SCAN_T - 1];
        __syncthreads();
    }
}

__global__ __launch_bounds__(SCAN_T) void k_scan3(int* __restrict__ G,
                                                  const int* __restrict__ part, int NG) {
    int i = blockIdx.x * SCAN_T + threadIdx.x;
    if (i < NG) G[i] += part[blockIdx.x];
}

// --- coarse scatter into bucket order
__global__ __launch_bounds__(256) void k_place(const int* __restrict__ src,
                                               const int* __restrict__ dst,
                                               const int* __restrict__ Gs,
                                               int* __restrict__ packed,
                                               int chunk, int nbkt) {
    __shared__ int offs[128];
    int t = threadIdx.x, blk = blockIdx.x;
    if (t < nbkt) offs[t] = Gs[t * B1 + blk];
    __syncthreads();
    int s0 = blk * chunk, n4 = chunk >> 2;
    const int4* d4 = (const int4*)(dst + s0);
    const int4* s4 = (const int4*)(src + s0);
    for (int i = t; i < n4; i += 256) {
        int4 d = d4[i];
        int4 s = s4[i];
        int b, p;
        b = d.x >> CSH; p = atomicAdd(&offs[b], 1); packed[p] = ((d.x & CMASK) << 17) | s.x;
        b = d.y >> CSH; p = atomicAdd(&offs[b], 1); packed[p] = ((d.y & CMASK) << 17) | s.y;
        b = d.z >> CSH; p = atomicAdd(&offs[b], 1); packed[p] = ((d.z & CMASK) << 17) | s.z;
        b = d.w >> CSH; p = atomicAdd(&offs[b], 1); packed[p] = ((d.w & CMASK) << 17) | s.w;
    }
}

// --- fine histogram: block (b,s) counts node-locals of its 1/S of bucket b
__global__ __launch_bounds__(AT) void k_deg(const int* __restrict__ packed,
                                            const int* __restrict__ Gs,
                                            int* __restrict__ Pdeg,
                                            int E, int nbkt) {
    __shared__ int cnt[C];
    int t = threadIdx.x, g = blockIdx.x;
    int b = g >> 3, s = g & 7;
    cnt[t] = 0; cnt[t + AT] = 0;
    __syncthreads();
    int st = Gs[b * B1];
    int en = (b == nbkt - 1) ? E : Gs[(b + 1) * B1];
    int len = en - st;
    int lo = st + ((len * s) >> 3);
    int hi = st + ((len * (s + 1)) >> 3);
    int i = lo + t;
    for (; i + 3 * AT < hi; i += 4 * AT) {
        int p0 = packed[i], p1 = packed[i + AT], p2 = packed[i + 2 * AT], p3 = packed[i + 3 * AT];
        atomicAdd(&cnt[p0 >> 17], 1);
        atomicAdd(&cnt[p1 >> 17], 1);
        atomicAdd(&cnt[p2 >> 17], 1);
        atomicAdd(&cnt[p3 >> 17], 1);
    }
    for (; i < hi; i += AT)
        atomicAdd(&cnt[packed[i] >> 17], 1);
    __syncthreads();
    Pdeg[(size_t)g * C + t] = cnt[t];
    Pdeg[(size_t)g * C + t + AT] = cnt[t + AT];
}

// --- per-bucket scan of node totals -> NodeOff, dinv, y
__global__ __launch_bounds__(1024) void k_fscan(const int* __restrict__ Pdeg,
                                                const int* __restrict__ Gs,
                                                const float* __restrict__ x,
                                                int* __restrict__ NodeOff,
                                                float* __restrict__ dinv,
                                                float* __restrict__ y,
                                                int N, int E, int nbkt) {
    __shared__ int sh[C];
    int b = blockIdx.x, l = threadIdx.x;
    int tot = 0;
#pragma unroll
    for (int s = 0; s < S; s++)
        tot += Pdeg[(size_t)(b * S + s) * C + l];
    sh[l] = tot;
    __syncthreads();
    for (int off = 1; off < C; off <<= 1) {
        int u = (l >= off) ? sh[l - off] : 0;
        __syncthreads();
        sh[l] += u;
        __syncthreads();
    }
    int start = Gs[b * B1] + sh[l] - tot;   // bucket base + exclusive prefix
    int node = (b << CSH) + l;
    NodeOff[node] = start;
    if (b == nbkt - 1 && l == C - 1) NodeOff[node + 1] = E;
    if (node < N) {
        float di = rsqrtf((float)tot + 1.0f);   // +1 self-loop
        dinv[node] = di;
        y[node] = di * x[node];
    }
}

// --- fine place, node-partitioned: block (b,s) owns nodes [s*128,(s+1)*128)
//     of bucket b; scans the whole bucket, stages its edges in LDS, flushes
//     coalesced. Fallback: direct scatter if staging would overflow.
__global__ __launch_bounds__(256) void k_fplace(const int* __restrict__ packed,
                                                const int* __restrict__ Gs,
                                                const int* __restrict__ NodeOff,
                                                int* __restrict__ packed2,
                                                int E, int nbkt) {
    __shared__ int cur[128];
    __shared__ int stage[FCAP];
    int t = threadIdx.x, g = blockIdx.x;
    int b = g >> 3, s = g & 7;
    int nlo = (b << CSH) + (s << 7);       // first owned node (padded index)
    if (t < 128) cur[t] = NodeOff[nlo + t];
    __syncthreads();
    int base  = NodeOff[nlo];
    int total = NodeOff[nlo + 128] - base;
    int st = Gs[b * B1];
    int en = (b == nbkt - 1) ? E : Gs[(b + 1) * B1];

    if (total <= FCAP) {
        int i = st + t;
        for (; i + 3 * 256 < en; i += 4 * 256) {
            int p0 = packed[i], p1 = packed[i + 256], p2 = packed[i + 512], p3 = packed[i + 768];
            int l0 = p0 >> 17, l1 = p1 >> 17, l2 = p2 >> 17, l3 = p3 >> 17;
            if ((l0 >> 7) == s) { int q = atomicAdd(&cur[l0 & 127], 1); stage[q - base] = p0 & 0x1FFFF; }
            if ((l1 >> 7) == s) { int q = atomicAdd(&cur[l1 & 127], 1); stage[q - base] = p1 & 0x1FFFF; }
            if ((l2 >> 7) == s) { int q = atomicAdd(&cur[l2 & 127], 1); stage[q - base] = p2 & 0x1FFFF; }
            if ((l3 >> 7) == s) { int q = atomicAdd(&cur[l3 & 127], 1); stage[q - base] = p3 & 0x1FFFF; }
        }
        for (; i < en; i += 256) {
            int p = packed[i], l = p >> 17;
            if ((l >> 7) == s) { int q = atomicAdd(&cur[l & 127], 1); stage[q - base] = p & 0x1FFFF; }
        }
        __syncthreads();
        for (int j = t; j < total; j += 256) packed2[base + j] = stage[j];
    } else {
        // overflow fallback (probability ~0; correctness guarantee)
        for (int i = st + t; i < en; i += 256) {
            int p = packed[i], l = p >> 17;
            if ((l >> 7) == s) { int q = atomicAdd(&cur[l & 127], 1); packed2[q] = p & 0x1FFFF; }
        }
    }
}

// --- layer-1: register run-sum + fused 1->16 relu MLP -> 16->2 (no atomics)
__global__ __launch_bounds__(128) void k_agg1m(const int* __restrict__ packed2,
                                               const int* __restrict__ NodeOff,
                                               const float* __restrict__ dinv,
                                               const float* __restrict__ y,
                                               const float* __restrict__ W1,
                                               const float* __restrict__ b1,
                                               const float* __restrict__ W2,
                                               float2* __restrict__ gy, int N) {
    int node = blockIdx.x * 128 + threadIdx.x;
    int st = NodeOff[node], en = NodeOff[node + 1];
    float sum = 0.f;
    int i = st;
    for (; i + 3 < en; i += 4) {
        int s0 = packed2[i], s1 = packed2[i + 1], s2 = packed2[i + 2], s3 = packed2[i + 3];
        sum += y[s0] + y[s1] + y[s2] + y[s3];
    }
    for (; i < en; i++) sum += y[packed2[i]];
    if (node < N) {
        float di = dinv[node];
        float Sv = di * (sum + y[node]);        // self-loop adds y[node]
        float g0 = 0.f, g1 = 0.f;
#pragma unroll
        for (int f = 0; f < 16; f++) {
            float h = fmaxf(fmaf(W1[f], Sv, b1[f]), 0.f);
            g0 = fmaf(h, W2[2 * f], g0);
            g1 = fmaf(h, W2[2 * f + 1], g1);
        }
        gy[node] = make_float2(di * g0, di * g1);  // premultiplied by dinv[src]
    }
}

// --- layer-2: register run-sum + bias + log_softmax (no atomics)
__global__ __launch_bounds__(128) void k_agg2o(const int* __restrict__ packed2,
                                               const int* __restrict__ NodeOff,
                                               const float* __restrict__ dinv,
                                               const float2* __restrict__ gy,
                                               const float* __restrict__ b2,
                                               float2* __restrict__ out, int N) {
    int node = blockIdx.x * 128 + threadIdx.x;
    int st = NodeOff[node], en = NodeOff[node + 1];
    float t0 = 0.f, t1 = 0.f;
    int i = st;
    for (; i + 3 < en; i += 4) {
        float2 v0 = gy[packed2[i]];
        float2 v1 = gy[packed2[i + 1]];
        float2 v2 = gy[packed2[i + 2]];
        float2 v3 = gy[packed2[i + 3]];
        t0 += v0.x + v1.x + v2.x + v3.x;
        t1 += v0.y + v1.y + v2.y + v3.y;
    }
    for (; i < en; i++) {
        float2 v = gy[packed2[i]];
        t0 += v.x; t1 += v.y;
    }
    if (node < N) {
        float di = dinv[node];
        float2 g = gy[node];
        float z0 = di * (t0 + g.x) + b2[0];
        float z1 = di * (t1 + g.y) + b2[1];
        float m = fmaxf(z0, z1);
        float lse = logf(expf(z0 - m) + expf(z1 - m));
        out[node] = make_float2(z0 - m - lse, z1 - m - lse);
    }
}

extern "C" void kernel_launch(void* const* d_in, const int* in_sizes, int n_in,
                              void* d_out, int out_size, void* d_ws, size_t ws_size,
                              hipStream_t stream) {
    const float* x  = (const float*)d_in[0];
    const int* ei   = (const int*)d_in[1];
    const float* W1 = (const float*)d_in[2];
    const float* b1 = (const float*)d_in[3];
    const float* W2 = (const float*)d_in[4];
    const float* b2 = (const float*)d_in[5];

    const int N = in_sizes[0];        // 100000
    const int E = in_sizes[1] / 2;    // 6400000
    const int* src = ei;
    const int* dst = ei + E;

    const int nbkt  = (N + CMASK) >> CSH;    // 98
    const int chunk = E / B1;                // 25000
    const int NP    = nbkt * B1;             // 25088 = 49 * 512 exactly
    const int scanB = NP / SCAN_T;           // 49
    const int gF    = nbkt * S;              // 784 fine blocks
    const int np    = nbkt << CSH;           // 100352 (padded nodes)

    // ws layout (ints): packed[E] | G[NP] | part[scanB] | Pdeg[gF*C] |
    //                   NodeOff[np+1] | dinv[np] | y[np] | gy[2np] | packed2?
    int* packed  = (int*)d_ws;
    int* G       = packed + E;
    int* part    = G + NP;
    int* Pdeg    = part + scanB;
    int* NodeOff = Pdeg + (size_t)gF * C;
    float* dinv  = (float*)(NodeOff + np + 1);
    float* y     = dinv + np;
    float2* gy   = (float2*)(y + np);
    int* tail    = (int*)(gy + np);
    size_t used  = (size_t)((char*)tail - (char*)d_ws);
    // packed2 in ws if it fits, else reuse edge_index's src half (consumed by
    // k_place before k_fplace writes it; harness restores inputs per launch;
    // every packed2 slot is rewritten before any read within each launch).
    int* packed2 = (used + (size_t)E * sizeof(int) <= ws_size)
                       ? tail : (int*)d_in[1];

    k_hist  <<<B1,       256,    0, stream>>>(dst, G, chunk, nbkt);
    k_scan1 <<<scanB,    SCAN_T, 0, stream>>>(G, part, NP);
    k_scan2 <<<1,        SCAN_T, 0, stream>>>(part, scanB);
    k_scan3 <<<scanB,    SCAN_T, 0, stream>>>(G, part, NP);
    k_place <<<B1,       256,    0, stream>>>(src, dst, G, packed, chunk, nbkt);
    k_deg   <<<gF,       AT,     0, stream>>>(packed, G, Pdeg, E, nbkt);
    k_fscan <<<nbkt,     C,      0, stream>>>(Pdeg, G, x, NodeOff, dinv, y, N, E, nbkt);
    k_fplace<<<gF,       256,    0, stream>>>(packed, G, NodeOff, packed2, E, nbkt);
    k_agg1m <<<np / 128, 128,    0, stream>>>(packed2, NodeOff, dinv, y, W1, b1, W2, gy, N);
    k_agg2o <<<np / 128, 128,    0, stream>>>(packed2, NodeOff, dinv, gy, b2, (float2*)d_out, N);
}

// Round 9
// 281.568 us; speedup vs baseline: 1.2946x; 1.1356x over previous
//
#include <hip/hip_runtime.h>
#include <math.h>

// GCN 2-layer, N=100000, E=6400000, Fin=1, Fhid=16, Fout=2.
// R9 = R8 with k_fplace rebuilt: edge-partitioned (reads each edge ONCE,
// vs R8's 8x bucket re-read / 100MB fetch) with per-(bucket,split,node)
// cursors W (R7-proven k_fscan), and XCD-SWIZZLED block mapping: all 8
// splits of bucket b run on XCD b%8 (assuming round-robin blockIdx%8->XCD),
// so the bucket's read range is fetched into one L2 once and the scattered
// 4B writes of adjacent sub-runs merge into full lines in that same L2.
// 4KB LDS/block -> all 104 blocks/XCD co-resident -> splits concurrent.
// packed = (dst & 1023) << 17 | src  (src < 2^17); packed2 = src only.

#define CSH   10
#define CMASK 1023
#define C     1024
#define B1    256      // coarse sort blocks; chunk = E/B1 = 25000 (/4 exact)
#define S     8        // fine splits per bucket
#define SCAN_T 512
#define AT    512      // threads for k_deg / k_fplace

// --- coarse histogram of dst>>10 (4 per-wave sub-hists, 128 slots each)
__global__ __launch_bounds__(256) void k_hist(const int* __restrict__ dst,
                                              int* __restrict__ G,
                                              int chunk, int nbkt) {
    __shared__ int sh[512];
    int t = threadIdx.x, blk = blockIdx.x;
    sh[t] = 0; sh[t + 256] = 0;
    __syncthreads();
    int w = (t >> 6) << 7;
    const int4* d4 = (const int4*)(dst + blk * chunk);
    int n4 = chunk >> 2;
    for (int i = t; i < n4; i += 256) {
        int4 d = d4[i];
        atomicAdd(&sh[w + (d.x >> CSH)], 1);
        atomicAdd(&sh[w + (d.y >> CSH)], 1);
        atomicAdd(&sh[w + (d.z >> CSH)], 1);
        atomicAdd(&sh[w + (d.w >> CSH)], 1);
    }
    __syncthreads();
    if (t < nbkt)
        G[t * B1 + blk] = sh[t] + sh[128 + t] + sh[256 + t] + sh[384 + t];
}

// --- 3-phase parallel exclusive scan over G[NP] (bucket-major)
__global__ __launch_bounds__(SCAN_T) void k_scan1(int* __restrict__ G,
                                                  int* __restrict__ part, int NG) {
    __shared__ int sh[SCAN_T];
    int t = threadIdx.x;
    int i = blockIdx.x * SCAN_T + t;
    int v = (i < NG) ? G[i] : 0;
    sh[t] = v;
    __syncthreads();
    for (int off = 1; off < SCAN_T; off <<= 1) {
        int u = (t >= off) ? sh[t - off] : 0;
        __syncthreads();
        sh[t] += u;
        __syncthreads();
    }
    if (i < NG) G[i] = sh[t] - v;
    if (t == SCAN_T - 1) part[blockIdx.x] = sh[t];
}

__global__ __launch_bounds__(SCAN_T) void k_scan2(int* __restrict__ part, int NP) {
    __shared__ int sh[SCAN_T];
    int t = threadIdx.x;
    int carry = 0;
    for (int base = 0; base < NP; base += SCAN_T) {
        int i = base + t;
        int v = (i < NP) ? part[i] : 0;
        sh[t] = v;
        __syncthreads();
        for (int off = 1; off < SCAN_T; off <<= 1) {
            int u = (t >= off) ? sh[t - off] : 0;
            __syncthreads();
            sh[t] += u;
            __syncthreads();
        }
        if (i < NP) part[i] = carry + sh[t] - v;
        carry += sh[SCAN_T - 1];
        __syncthreads();
    }
}

__global__ __launch_bounds__(SCAN_T) void k_scan3(int* __restrict__ G,
                                                  const int* __restrict__ part, int NG) {
    int i = blockIdx.x * SCAN_T + threadIdx.x;
    if (i < NG) G[i] += part[blockIdx.x];
}

// --- coarse scatter into bucket order
__global__ __launch_bounds__(256) void k_place(const int* __restrict__ src,
                                               const int* __restrict__ dst,
                                               const int* __restrict__ Gs,
                                               int* __restrict__ packed,
                                               int chunk, int nbkt) {
    __shared__ int offs[128];
    int t = threadIdx.x, blk = blockIdx.x;
    if (t < nbkt) offs[t] = Gs[t * B1 + blk];
    __syncthreads();
    int s0 = blk * chunk, n4 = chunk >> 2;
    const int4* d4 = (const int4*)(dst + s0);
    const int4* s4 = (const int4*)(src + s0);
    for (int i = t; i < n4; i += 256) {
        int4 d = d4[i];
        int4 s = s4[i];
        int b, p;
        b = d.x >> CSH; p = atomicAdd(&offs[b], 1); packed[p] = ((d.x & CMASK) << 17) | s.x;
        b = d.y >> CSH; p = atomicAdd(&offs[b], 1); packed[p] = ((d.y & CMASK) << 17) | s.y;
        b = d.z >> CSH; p = atomicAdd(&offs[b], 1); packed[p] = ((d.z & CMASK) << 17) | s.z;
        b = d.w >> CSH; p = atomicAdd(&offs[b], 1); packed[p] = ((d.w & CMASK) << 17) | s.w;
    }
}

// --- fine histogram: block (b,s) counts node-locals of its 1/S of bucket b
__global__ __launch_bounds__(AT) void k_deg(const int* __restrict__ packed,
                                            const int* __restrict__ Gs,
                                            int* __restrict__ Pdeg,
                                            int E, int nbkt) {
    __shared__ int cnt[C];
    int t = threadIdx.x, g = blockIdx.x;
    int b = g >> 3, s = g & 7;
    cnt[t] = 0; cnt[t + AT] = 0;
    __syncthreads();
    int st = Gs[b * B1];
    int en = (b == nbkt - 1) ? E : Gs[(b + 1) * B1];
    int len = en - st;
    int lo = st + ((len * s) >> 3);
    int hi = st + ((len * (s + 1)) >> 3);
    int i = lo + t;
    for (; i + 3 * AT < hi; i += 4 * AT) {
        int p0 = packed[i], p1 = packed[i + AT], p2 = packed[i + 2 * AT], p3 = packed[i + 3 * AT];
        atomicAdd(&cnt[p0 >> 17], 1);
        atomicAdd(&cnt[p1 >> 17], 1);
        atomicAdd(&cnt[p2 >> 17], 1);
        atomicAdd(&cnt[p3 >> 17], 1);
    }
    for (; i < hi; i += AT)
        atomicAdd(&cnt[packed[i] >> 17], 1);
    __syncthreads();
    Pdeg[(size_t)g * C + t] = cnt[t];
    Pdeg[(size_t)g * C + t + AT] = cnt[t + AT];
}

// --- per-bucket scan: node run offsets NodeOff, per-split cursors W, dinv, y
__global__ __launch_bounds__(1024) void k_fscan(const int* __restrict__ Pdeg,
                                                const int* __restrict__ Gs,
                                                const float* __restrict__ x,
                                                int* __restrict__ W,
                                                int* __restrict__ NodeOff,
                                                float* __restrict__ dinv,
                                                float* __restrict__ y,
                                                int N, int E, int nbkt) {
    __shared__ int sh[C];
    int b = blockIdx.x, l = threadIdx.x;
    int c[S];
    int tot = 0;
#pragma unroll
    for (int s = 0; s < S; s++) {
        c[s] = Pdeg[(size_t)(b * S + s) * C + l];
        tot += c[s];
    }
    sh[l] = tot;
    __syncthreads();
    for (int off = 1; off < C; off <<= 1) {
        int u = (l >= off) ? sh[l - off] : 0;
        __syncthreads();
        sh[l] += u;
        __syncthreads();
    }
    int start = Gs[b * B1] + sh[l] - tot;   // bucket base + exclusive prefix
    int node = (b << CSH) + l;
    NodeOff[node] = start;
    if (b == nbkt - 1 && l == C - 1) NodeOff[node + 1] = E;
    int run = start;
#pragma unroll
    for (int s = 0; s < S; s++) {
        W[(size_t)(b * S + s) * C + l] = run;
        run += c[s];
    }
    if (node < N) {
        float di = rsqrtf((float)tot + 1.0f);   // +1 self-loop
        dinv[node] = di;
        y[node] = di * x[node];
    }
}

// --- fine place: edge-partitioned (1x read), XCD-swizzled so all 8 splits
//     of bucket b run on XCD b%8 -> shared-L2 read + write-combining.
__global__ __launch_bounds__(AT) void k_fplace(const int* __restrict__ packed,
                                               const int* __restrict__ Gs,
                                               const int* __restrict__ W,
                                               int* __restrict__ packed2,
                                               int E, int nbkt) {
    __shared__ int cur[C];
    int g = blockIdx.x;
    int x = g & 7, j = g >> 3;          // x = XCD (assumes round-robin %8)
    int b = x + ((j >> 3) << 3);        // b ≡ x (mod 8)
    int s = j & 7;
    if (b >= nbkt) return;
    int t = threadIdx.x;
    cur[t]      = W[(size_t)(b * S + s) * C + t];
    cur[t + AT] = W[(size_t)(b * S + s) * C + t + AT];
    __syncthreads();
    int st = Gs[b * B1];
    int en = (b == nbkt - 1) ? E : Gs[(b + 1) * B1];
    int len = en - st;
    int lo = st + ((len * s) >> 3);
    int hi = st + ((len * (s + 1)) >> 3);
    int i = lo + t;
    for (; i + 3 * AT < hi; i += 4 * AT) {
        int p0 = packed[i], p1 = packed[i + AT], p2 = packed[i + 2 * AT], p3 = packed[i + 3 * AT];
        int q0 = atomicAdd(&cur[p0 >> 17], 1);
        int q1 = atomicAdd(&cur[p1 >> 17], 1);
        int q2 = atomicAdd(&cur[p2 >> 17], 1);
        int q3 = atomicAdd(&cur[p3 >> 17], 1);
        packed2[q0] = p0 & 0x1FFFF;
        packed2[q1] = p1 & 0x1FFFF;
        packed2[q2] = p2 & 0x1FFFF;
        packed2[q3] = p3 & 0x1FFFF;
    }
    for (; i < hi; i += AT) {
        int p = packed[i];
        int q = atomicAdd(&cur[p >> 17], 1);
        packed2[q] = p & 0x1FFFF;
    }
}

// --- layer-1: register run-sum + fused 1->16 relu MLP -> 16->2 (no atomics)
__global__ __launch_bounds__(128) void k_agg1m(const int* __restrict__ packed2,
                                               const int* __restrict__ NodeOff,
                                               const float* __restrict__ dinv,
                                               const float* __restrict__ y,
                                               const float* __restrict__ W1,
                                               const float* __restrict__ b1,
                                               const float* __restrict__ W2,
                                               float2* __restrict__ gy, int N) {
    int node = blockIdx.x * 128 + threadIdx.x;
    int st = NodeOff[node], en = NodeOff[node + 1];
    float sum = 0.f;
    int i = st;
    for (; i + 3 < en; i += 4) {
        int s0 = packed2[i], s1 = packed2[i + 1], s2 = packed2[i + 2], s3 = packed2[i + 3];
        sum += y[s0] + y[s1] + y[s2] + y[s3];
    }
    for (; i < en; i++) sum += y[packed2[i]];
    if (node < N) {
        float di = dinv[node];
        float Sv = di * (sum + y[node]);        // self-loop adds y[node]
        float g0 = 0.f, g1 = 0.f;
#pragma unroll
        for (int f = 0; f < 16; f++) {
            float h = fmaxf(fmaf(W1[f], Sv, b1[f]), 0.f);
            g0 = fmaf(h, W2[2 * f], g0);
            g1 = fmaf(h, W2[2 * f + 1], g1);
        }
        gy[node] = make_float2(di * g0, di * g1);  // premultiplied by dinv[src]
    }
}

// --- layer-2: register run-sum + bias + log_softmax (no atomics)
__global__ __launch_bounds__(128) void k_agg2o(const int* __restrict__ packed2,
                                               const int* __restrict__ NodeOff,
                                               const float* __restrict__ dinv,
                                               const float2* __restrict__ gy,
                                               const float* __restrict__ b2,
                                               float2* __restrict__ out, int N) {
    int node = blockIdx.x * 128 + threadIdx.x;
    int st = NodeOff[node], en = NodeOff[node + 1];
    float t0 = 0.f, t1 = 0.f;
    int i = st;
    for (; i + 3 < en; i += 4) {
        float2 v0 = gy[packed2[i]];
        float2 v1 = gy[packed2[i + 1]];
        float2 v2 = gy[packed2[i + 2]];
        float2 v3 = gy[packed2[i + 3]];
        t0 += v0.x + v1.x + v2.x + v3.x;
        t1 += v0.y + v1.y + v2.y + v3.y;
    }
    for (; i < en; i++) {
        float2 v = gy[packed2[i]];
        t0 += v.x; t1 += v.y;
    }
    if (node < N) {
        float di = dinv[node];
        float2 g = gy[node];
        float z0 = di * (t0 + g.x) + b2[0];
        float z1 = di * (t1 + g.y) + b2[1];
        float m = fmaxf(z0, z1);
        float lse = logf(expf(z0 - m) + expf(z1 - m));
        out[node] = make_float2(z0 - m - lse, z1 - m - lse);
    }
}

extern "C" void kernel_launch(void* const* d_in, const int* in_sizes, int n_in,
                              void* d_out, int out_size, void* d_ws, size_t ws_size,
                              hipStream_t stream) {
    const float* x  = (const float*)d_in[0];
    const int* ei   = (const int*)d_in[1];
    const float* W1 = (const float*)d_in[2];
    const float* b1 = (const float*)d_in[3];
    const float* W2 = (const float*)d_in[4];
    const float* b2 = (const float*)d_in[5];

    const int N = in_sizes[0];        // 100000
    const int E = in_sizes[1] / 2;    // 6400000
    const int* src = ei;
    const int* dst = ei + E;

    const int nbkt  = (N + CMASK) >> CSH;    // 98
    const int chunk = E / B1;                // 25000
    const int NP    = nbkt * B1;             // 25088 = 49 * 512 exactly
    const int scanB = NP / SCAN_T;           // 49
    const int gF    = nbkt * S;              // 784 fine blocks (deg)
    const int gFP   = 104 * 8;               // 832 swizzled fplace blocks
    const int np    = nbkt << CSH;           // 100352 (padded nodes)

    // ws (ints): packed[E] | G[NP] | part[scanB] | Pdeg[gF*C] | W[gF*C] |
    //            NodeOff[np+1] | dinv[np] | y[np] | gy[2np] | packed2?
    int* packed  = (int*)d_ws;
    int* G       = packed + E;
    int* part    = G + NP;
    int* Pdeg    = part + scanB;
    int* W       = Pdeg + (size_t)gF * C;
    int* NodeOff = W + (size_t)gF * C;
    float* dinv  = (float*)(NodeOff + np + 1);
    float* y     = dinv + np;
    float2* gy   = (float2*)(y + np);
    int* tail    = (int*)(gy + np);
    size_t used  = (size_t)((char*)tail - (char*)d_ws);
    // packed2 in ws if it fits, else reuse edge_index's src half (fully
    // consumed by k_place before k_fplace writes it; harness restores d_in
    // before every launch; every packed2 slot rewritten before any read).
    int* packed2 = (used + (size_t)E * sizeof(int) <= ws_size)
                       ? tail : (int*)d_in[1];

    k_hist  <<<B1,       256,    0, stream>>>(dst, G, chunk, nbkt);
    k_scan1 <<<scanB,    SCAN_T, 0, stream>>>(G, part, NP);
    k_scan2 <<<1,        SCAN_T, 0, stream>>>(part, scanB);
    k_scan3 <<<scanB,    SCAN_T, 0, stream>>>(G, part, NP);
    k_place <<<B1,       256,    0, stream>>>(src, dst, G, packed, chunk, nbkt);
    k_deg   <<<gF,       AT,     0, stream>>>(packed, G, Pdeg, E, nbkt);
    k_fscan <<<nbkt,     C,      0, stream>>>(Pdeg, G, x, W, NodeOff, dinv, y, N, E, nbkt);
    k_fplace<<<gFP,      AT,     0, stream>>>(packed, G, W, packed2, E, nbkt);
    k_agg1m <<<np / 128, 128,    0, stream>>>(packed2, NodeOff, dinv, y, W1, b1, W2, gy, N);
    k_agg2o <<<np / 128, 128,    0, stream>>>(packed2, NodeOff, dinv, gy, b2, (float2*)d_out, N);
}

// Round 10
// 266.980 us; speedup vs baseline: 1.3654x; 1.0546x over previous
//
#include <hip/hip_runtime.h>
#include <math.h>

// GCN 2-layer, N=100000, E=6400000, Fin=1, Fhid=16, Fout=2.
// R10 = R9 (two-level counting sort to full dst order, XCD-swizzled fplace)
// with the agg kernels rebuilt as SORTED-RUN REDUCERS:
//   packed2 now keeps (local<<17)|src (bits 0..26). Each 256-thread block
//   owns 128 nodes and their contiguous edge range (~8192 edges), stages it
//   coalesced into LDS, and each thread reduces an equal slice: interior
//   keys -> plain exclusive LDS store; boundary keys (<=2/thread) -> LDS
//   atomic. 16x fewer LDS atomics than accumulate-by-key; loads coalesced;
//   MLP / log_softmax epilogue fused in-block. Fallback to per-node serial
//   walk if a block's range exceeds the 10240-int staging cap (+22 sigma).
// R9 post-mortem: agg walks were latency-bound (48us @ 12% occ); sort passes
// sit at the measured LDS-atomic rate (~4.3 cyc/edge -> ~45us/pass).

#define CSH   10
#define CMASK 1023
#define C     1024
#define B1    256      // coarse sort blocks; chunk = E/B1 = 25000 (/4 exact)
#define S     8        // fine splits per bucket
#define SCAN_T 512
#define AT    512      // threads for k_deg / k_fplace
#define ACAP  10240    // agg staging ints (40 KB)

// --- coarse histogram of dst>>10 (4 per-wave sub-hists, 128 slots each)
__global__ __launch_bounds__(256) void k_hist(const int* __restrict__ dst,
                                              int* __restrict__ G,
                                              int chunk, int nbkt) {
    __shared__ int sh[512];
    int t = threadIdx.x, blk = blockIdx.x;
    sh[t] = 0; sh[t + 256] = 0;
    __syncthreads();
    int w = (t >> 6) << 7;
    const int4* d4 = (const int4*)(dst + blk * chunk);
    int n4 = chunk >> 2;
    for (int i = t; i < n4; i += 256) {
        int4 d = d4[i];
        atomicAdd(&sh[w + (d.x >> CSH)], 1);
        atomicAdd(&sh[w + (d.y >> CSH)], 1);
        atomicAdd(&sh[w + (d.z >> CSH)], 1);
        atomicAdd(&sh[w + (d.w >> CSH)], 1);
    }
    __syncthreads();
    if (t < nbkt)
        G[t * B1 + blk] = sh[t] + sh[128 + t] + sh[256 + t] + sh[384 + t];
}

// --- 3-phase parallel exclusive scan over G[NP] (bucket-major)
__global__ __launch_bounds__(SCAN_T) void k_scan1(int* __restrict__ G,
                                                  int* __restrict__ part, int NG) {
    __shared__ int sh[SCAN_T];
    int t = threadIdx.x;
    int i = blockIdx.x * SCAN_T + t;
    int v = (i < NG) ? G[i] : 0;
    sh[t] = v;
    __syncthreads();
    for (int off = 1; off < SCAN_T; off <<= 1) {
        int u = (t >= off) ? sh[t - off] : 0;
        __syncthreads();
        sh[t] += u;
        __syncthreads();
    }
    if (i < NG) G[i] = sh[t] - v;
    if (t == SCAN_T - 1) part[blockIdx.x] = sh[t];
}

__global__ __launch_bounds__(SCAN_T) void k_scan2(int* __restrict__ part, int NP) {
    __shared__ int sh[SCAN_T];
    int t = threadIdx.x;
    int carry = 0;
    for (int base = 0; base < NP; base += SCAN_T) {
        int i = base + t;
        int v = (i < NP) ? part[i] : 0;
        sh[t] = v;
        __syncthreads();
        for (int off = 1; off < SCAN_T; off <<= 1) {
            int u = (t >= off) ? sh[t - off] : 0;
            __syncthreads();
            sh[t] += u;
            __syncthreads();
        }
        if (i < NP) part[i] = carry + sh[t] - v;
        carry += sh[SCAN_T - 1];
        __syncthreads();
    }
}

__global__ __launch_bounds__(SCAN_T) void k_scan3(int* __restrict__ G,
                                                  const int* __restrict__ part, int NG) {
    int i = blockIdx.x * SCAN_T + threadIdx.x;
    if (i < NG) G[i] += part[blockIdx.x];
}

// --- coarse scatter into bucket order
__global__ __launch_bounds__(256) void k_place(const int* __restrict__ src,
                                               const int* __restrict__ dst,
                                               const int* __restrict__ Gs,
                                               int* __restrict__ packed,
                                               int chunk, int nbkt) {
    __shared__ int offs[128];
    int t = threadIdx.x, blk = blockIdx.x;
    if (t < nbkt) offs[t] = Gs[t * B1 + blk];
    __syncthreads();
    int s0 = blk * chunk, n4 = chunk >> 2;
    const int4* d4 = (const int4*)(dst + s0);
    const int4* s4 = (const int4*)(src + s0);
    for (int i = t; i < n4; i += 256) {
        int4 d = d4[i];
        int4 s = s4[i];
        int b, p;
        b = d.x >> CSH; p = atomicAdd(&offs[b], 1); packed[p] = ((d.x & CMASK) << 17) | s.x;
        b = d.y >> CSH; p = atomicAdd(&offs[b], 1); packed[p] = ((d.y & CMASK) << 17) | s.y;
        b = d.z >> CSH; p = atomicAdd(&offs[b], 1); packed[p] = ((d.z & CMASK) << 17) | s.z;
        b = d.w >> CSH; p = atomicAdd(&offs[b], 1); packed[p] = ((d.w & CMASK) << 17) | s.w;
    }
}

// --- fine histogram: block (b,s) counts node-locals of its 1/S of bucket b
__global__ __launch_bounds__(AT) void k_deg(const int* __restrict__ packed,
                                            const int* __restrict__ Gs,
                                            int* __restrict__ Pdeg,
                                            int E, int nbkt) {
    __shared__ int cnt[C];
    int t = threadIdx.x, g = blockIdx.x;
    int b = g >> 3, s = g & 7;
    cnt[t] = 0; cnt[t + AT] = 0;
    __syncthreads();
    int st = Gs[b * B1];
    int en = (b == nbkt - 1) ? E : Gs[(b + 1) * B1];
    int len = en - st;
    int lo = st + ((len * s) >> 3);
    int hi = st + ((len * (s + 1)) >> 3);
    int i = lo + t;
    for (; i + 3 * AT < hi; i += 4 * AT) {
        int p0 = packed[i], p1 = packed[i + AT], p2 = packed[i + 2 * AT], p3 = packed[i + 3 * AT];
        atomicAdd(&cnt[p0 >> 17], 1);
        atomicAdd(&cnt[p1 >> 17], 1);
        atomicAdd(&cnt[p2 >> 17], 1);
        atomicAdd(&cnt[p3 >> 17], 1);
    }
    for (; i < hi; i += AT)
        atomicAdd(&cnt[packed[i] >> 17], 1);
    __syncthreads();
    Pdeg[(size_t)g * C + t] = cnt[t];
    Pdeg[(size_t)g * C + t + AT] = cnt[t + AT];
}

// --- per-bucket scan: node run offsets NodeOff, per-split cursors W, dinv, y
__global__ __launch_bounds__(1024) void k_fscan(const int* __restrict__ Pdeg,
                                                const int* __restrict__ Gs,
                                                const float* __restrict__ x,
                                                int* __restrict__ W,
                                                int* __restrict__ NodeOff,
                                                float* __restrict__ dinv,
                                                float* __restrict__ y,
                                                int N, int E, int nbkt) {
    __shared__ int sh[C];
    int b = blockIdx.x, l = threadIdx.x;
    int c[S];
    int tot = 0;
#pragma unroll
    for (int s = 0; s < S; s++) {
        c[s] = Pdeg[(size_t)(b * S + s) * C + l];
        tot += c[s];
    }
    sh[l] = tot;
    __syncthreads();
    for (int off = 1; off < C; off <<= 1) {
        int u = (l >= off) ? sh[l - off] : 0;
        __syncthreads();
        sh[l] += u;
        __syncthreads();
    }
    int start = Gs[b * B1] + sh[l] - tot;   // bucket base + exclusive prefix
    int node = (b << CSH) + l;
    NodeOff[node] = start;
    if (b == nbkt - 1 && l == C - 1) NodeOff[node + 1] = E;
    int run = start;
#pragma unroll
    for (int s = 0; s < S; s++) {
        W[(size_t)(b * S + s) * C + l] = run;
        run += c[s];
    }
    if (node < N) {
        float di = rsqrtf((float)tot + 1.0f);   // +1 self-loop
        dinv[node] = di;
        y[node] = di * x[node];
    }
}

// --- fine place: edge-partitioned (1x read), XCD-swizzled (splits of bucket
//     b share XCD b%8 -> shared-L2 read + write-combining). Stores the whole
//     packed word (local<<17 | src) so agg can segment by local id.
__global__ __launch_bounds__(AT) void k_fplace(const int* __restrict__ packed,
                                               const int* __restrict__ Gs,
                                               const int* __restrict__ W,
                                               int* __restrict__ packed2,
                                               int E, int nbkt) {
    __shared__ int cur[C];
    int g = blockIdx.x;
    int x = g & 7, j = g >> 3;          // x = XCD (assumes round-robin %8)
    int b = x + ((j >> 3) << 3);        // b ≡ x (mod 8)
    int s = j & 7;
    if (b >= nbkt) return;
    int t = threadIdx.x;
    cur[t]      = W[(size_t)(b * S + s) * C + t];
    cur[t + AT] = W[(size_t)(b * S + s) * C + t + AT];
    __syncthreads();
    int st = Gs[b * B1];
    int en = (b == nbkt - 1) ? E : Gs[(b + 1) * B1];
    int len = en - st;
    int lo = st + ((len * s) >> 3);
    int hi = st + ((len * (s + 1)) >> 3);
    int i = lo + t;
    for (; i + 3 * AT < hi; i += 4 * AT) {
        int p0 = packed[i], p1 = packed[i + AT], p2 = packed[i + 2 * AT], p3 = packed[i + 3 * AT];
        int q0 = atomicAdd(&cur[p0 >> 17], 1);
        int q1 = atomicAdd(&cur[p1 >> 17], 1);
        int q2 = atomicAdd(&cur[p2 >> 17], 1);
        int q3 = atomicAdd(&cur[p3 >> 17], 1);
        packed2[q0] = p0;
        packed2[q1] = p1;
        packed2[q2] = p2;
        packed2[q3] = p3;
    }
    for (; i < hi; i += AT) {
        int p = packed[i];
        int q = atomicAdd(&cur[p >> 17], 1);
        packed2[q] = p;
    }
}

// --- layer-1: staged sorted-run reduce + fused 1->16 relu MLP -> 16->2
__global__ __launch_bounds__(256) void k_agg1m(const int* __restrict__ packed2,
                                               const int* __restrict__ NodeOff,
                                               const float* __restrict__ dinv,
                                               const float* __restrict__ y,
                                               const float* __restrict__ W1,
                                               const float* __restrict__ b1,
                                               const float* __restrict__ W2,
                                               float2* __restrict__ gy, int N) {
    __shared__ int stage[ACAP];
    __shared__ float acc[128];
    int t = threadIdx.x, g = blockIdx.x;
    int n0 = g << 7;
    int base = NodeOff[n0];
    int len = NodeOff[n0 + 128] - base;
    if (t < 128) acc[t] = 0.f;
    if (len <= ACAP) {
        for (int j = t; j < len; j += 256) stage[j] = packed2[base + j];
        __syncthreads();
        int lo = (len * t) >> 8;
        int hi = (len * (t + 1)) >> 8;
        if (lo < hi) {
            int w = stage[lo];
            int kprev = w >> 17;
            float run = y[w & 0x1FFFF];
            bool first = true;
            for (int j = lo + 1; j < hi; j++) {
                w = stage[j];
                int k = w >> 17;
                float v = y[w & 0x1FFFF];
                if (k != kprev) {
                    if (first) { atomicAdd(&acc[kprev & 127], run); first = false; }
                    else acc[kprev & 127] = run;   // interior key: exclusive
                    run = 0.f;
                    kprev = k;
                }
                run += v;
            }
            atomicAdd(&acc[kprev & 127], run);     // last key: may be shared
        }
        __syncthreads();
    } else {
        // fallback (never expected: len ~ Poisson(8192), cap +22 sigma)
        __syncthreads();
        if (t < 128) {
            int st = NodeOff[n0 + t], en = NodeOff[n0 + t + 1];
            float sum = 0.f;
            for (int i = st; i < en; i++) sum += y[packed2[i] & 0x1FFFF];
            acc[t] = sum;
        }
        __syncthreads();
    }
    if (t < 128) {
        int node = n0 + t;
        if (node < N) {
            float di = dinv[node];
            float Sv = di * (acc[t] + y[node]);    // self-loop adds y[node]
            float g0 = 0.f, g1 = 0.f;
#pragma unroll
            for (int f = 0; f < 16; f++) {
                float h = fmaxf(fmaf(W1[f], Sv, b1[f]), 0.f);
                g0 = fmaf(h, W2[2 * f], g0);
                g1 = fmaf(h, W2[2 * f + 1], g1);
            }
            gy[node] = make_float2(di * g0, di * g1);  // premul by dinv[src]
        }
    }
}

// --- layer-2: staged sorted-run reduce (float2) + bias + log_softmax
__global__ __launch_bounds__(256) void k_agg2o(const int* __restrict__ packed2,
                                               const int* __restrict__ NodeOff,
                                               const float* __restrict__ dinv,
                                               const float2* __restrict__ gy,
                                               const float* __restrict__ b2,
                                               float2* __restrict__ out, int N) {
    __shared__ int stage[ACAP];
    __shared__ float a0[128];
    __shared__ float a1[128];
    int t = threadIdx.x, g = blockIdx.x;
    int n0 = g << 7;
    int base = NodeOff[n0];
    int len = NodeOff[n0 + 128] - base;
    if (t < 128) { a0[t] = 0.f; a1[t] = 0.f; }
    if (len <= ACAP) {
        for (int j = t; j < len; j += 256) stage[j] = packed2[base + j];
        __syncthreads();
        int lo = (len * t) >> 8;
        int hi = (len * (t + 1)) >> 8;
        if (lo < hi) {
            int w = stage[lo];
            int kprev = w >> 17;
            float2 v = gy[w & 0x1FFFF];
            float r0 = v.x, r1 = v.y;
            bool first = true;
            for (int j = lo + 1; j < hi; j++) {
                w = stage[j];
                int k = w >> 17;
                v = gy[w & 0x1FFFF];
                if (k != kprev) {
                    int a = kprev & 127;
                    if (first) { atomicAdd(&a0[a], r0); atomicAdd(&a1[a], r1); first = false; }
                    else { a0[a] = r0; a1[a] = r1; }
                    r0 = 0.f; r1 = 0.f;
                    kprev = k;
                }
                r0 += v.x; r1 += v.y;
            }
            int a = kprev & 127;
            atomicAdd(&a0[a], r0); atomicAdd(&a1[a], r1);
        }
        __syncthreads();
    } else {
        __syncthreads();
        if (t < 128) {
            int st = NodeOff[n0 + t], en = NodeOff[n0 + t + 1];
            float s0 = 0.f, s1 = 0.f;
            for (int i = st; i < en; i++) {
                float2 v = gy[packed2[i] & 0x1FFFF];
                s0 += v.x; s1 += v.y;
            }
            a0[t] = s0; a1[t] = s1;
        }
        __syncthreads();
    }
    if (t < 128) {
        int node = n0 + t;
        if (node < N) {
            float di = dinv[node];
            float2 gv = gy[node];
            float z0 = di * (a0[t] + gv.x) + b2[0];
            float z1 = di * (a1[t] + gv.y) + b2[1];
            float m = fmaxf(z0, z1);
            float lse = logf(expf(z0 - m) + expf(z1 - m));
            out[node] = make_float2(z0 - m - lse, z1 - m - lse);
        }
    }
}

extern "C" void kernel_launch(void* const* d_in, const int* in_sizes, int n_in,
                              void* d_out, int out_size, void* d_ws, size_t ws_size,
                              hipStream_t stream) {
    const float* x  = (const float*)d_in[0];
    const int* ei   = (const int*)d_in[1];
    const float* W1 = (const float*)d_in[2];
    const float* b1 = (const float*)d_in[3];
    const float* W2 = (const float*)d_in[4];
    const float* b2 = (const float*)d_in[5];

    const int N = in_sizes[0];        // 100000
    const int E = in_sizes[1] / 2;    // 6400000
    const int* src = ei;
    const int* dst = ei + E;

    const int nbkt  = (N + CMASK) >> CSH;    // 98
    const int chunk = E / B1;                // 25000
    const int NP    = nbkt * B1;             // 25088 = 49 * 512 exactly
    const int scanB = NP / SCAN_T;           // 49
    const int gF    = nbkt * S;              // 784 fine blocks (deg)
    const int gFP   = 104 * 8;               // 832 swizzled fplace blocks
    const int np    = nbkt << CSH;           // 100352 (padded nodes)

    // ws (ints): packed[E] | G[NP] | part[scanB] | Pdeg[gF*C] | W[gF*C] |
    //            NodeOff[np+1] | dinv[np] | y[np] | gy[2np] | packed2?
    int* packed  = (int*)d_ws;
    int* G       = packed + E;
    int* part    = G + NP;
    int* Pdeg    = part + scanB;
    int* W       = Pdeg + (size_t)gF * C;
    int* NodeOff = W + (size_t)gF * C;
    float* dinv  = (float*)(NodeOff + np + 1);
    float* y     = dinv + np;
    float2* gy   = (float2*)(y + np);
    int* tail    = (int*)(gy + np);
    size_t used  = (size_t)((char*)tail - (char*)d_ws);
    // packed2 in ws if it fits, else reuse edge_index's src half (fully
    // consumed by k_place before k_fplace writes it; harness restores d_in
    // before every launch; every packed2 slot rewritten before any read).
    int* packed2 = (used + (size_t)E * sizeof(int) <= ws_size)
                       ? tail : (int*)d_in[1];

    k_hist  <<<B1,       256,    0, stream>>>(dst, G, chunk, nbkt);
    k_scan1 <<<scanB,    SCAN_T, 0, stream>>>(G, part, NP);
    k_scan2 <<<1,        SCAN_T, 0, stream>>>(part, scanB);
    k_scan3 <<<scanB,    SCAN_T, 0, stream>>>(G, part, NP);
    k_place <<<B1,       256,    0, stream>>>(src, dst, G, packed, chunk, nbkt);
    k_deg   <<<gF,       AT,     0, stream>>>(packed, G, Pdeg, E, nbkt);
    k_fscan <<<nbkt,     C,      0, stream>>>(Pdeg, G, x, W, NodeOff, dinv, y, N, E, nbkt);
    k_fplace<<<gFP,      AT,     0, stream>>>(packed, G, W, packed2, E, nbkt);
    k_agg1m <<<np / 128, 256,    0, stream>>>(packed2, NodeOff, dinv, y, W1, b1, W2, gy, N);
    k_agg2o <<<np / 128, 256,    0, stream>>>(packed2, NodeOff, dinv, gy, b2, (float2*)d_out, N);
}